// Round 1
// baseline (1696.681 us; speedup 1.0000x reference)
//
#include <hip/hip_runtime.h>
#include <hip/hip_bf16.h>

#define NN 65536
#define KK 2048
#define DD 128

// ---------------- prep: w2[k] = sum(W[k]*W[k]) ----------------
__global__ __launch_bounds__(256) void vq_prep_w(const float* __restrict__ Wd,
                                                 float* __restrict__ w2)
{
    int k = blockIdx.x * 256 + threadIdx.x;
    const float4* wp = reinterpret_cast<const float4*>(Wd + (size_t)k * DD);
    float s0 = 0.f, s1 = 0.f, s2 = 0.f, s3 = 0.f;
#pragma unroll
    for (int q = 0; q < 32; ++q) {
        float4 w = wp[q];
        s0 = fmaf(w.x, w.x, s0);
        s1 = fmaf(w.y, w.y, s1);
        s2 = fmaf(w.z, w.z, s2);
        s3 = fmaf(w.w, w.w, s3);
    }
    w2[k] = (s0 + s1) + (s2 + s3);
}

// ---------------- assign: per-row argmin over a K/4 slice ----------------
// One thread = one Z row (full row in 128 VGPRs). W row address is wave-uniform
// -> scalar loads; inner loop is pure v_fmac_f32 on 4 independent chains.
// dist mimics ref: fl(fl(z2 - fl(2*s)) + w2[k]); ties resolve to lowest k via
// packed (monotone_bits<<32)|k atomicMin.
__global__ __launch_bounds__(64) void vq_assign(const float* __restrict__ Z,
                                                const float* __restrict__ Wd,
                                                const float* __restrict__ w2,
                                                unsigned long long* __restrict__ cand)
{
    const int row = blockIdx.x * 64 + threadIdx.x;
    const int k0  = blockIdx.y * (KK / 4);

    const float4* zp = reinterpret_cast<const float4*>(Z + (size_t)row * DD);
    float4 z[32];
#pragma unroll
    for (int q = 0; q < 32; ++q) z[q] = zp[q];

    float z2;
    {
        float s0 = 0.f, s1 = 0.f, s2 = 0.f, s3 = 0.f;
#pragma unroll
        for (int q = 0; q < 32; ++q) {
            s0 = fmaf(z[q].x, z[q].x, s0);
            s1 = fmaf(z[q].y, z[q].y, s1);
            s2 = fmaf(z[q].z, z[q].z, s2);
            s3 = fmaf(z[q].w, z[q].w, s3);
        }
        z2 = (s0 + s1) + (s2 + s3);
    }

    unsigned long long best = ~0ull;
    for (int k = k0; k < k0 + KK / 4; ++k) {
        const float4* wp = reinterpret_cast<const float4*>(Wd + (size_t)k * DD);
        float a0 = 0.f, a1 = 0.f, a2 = 0.f, a3 = 0.f;
#pragma unroll
        for (int q = 0; q < 32; ++q) {
            float4 w = wp[q];
            a0 = fmaf(z[q].x, w.x, a0);
            a1 = fmaf(z[q].y, w.y, a1);
            a2 = fmaf(z[q].z, w.z, a2);
            a3 = fmaf(z[q].w, w.w, a3);
        }
        float s    = (a0 + a1) + (a2 + a3);
        float t    = __fsub_rn(z2, __fmul_rn(2.0f, s));
        float dist = __fadd_rn(t, w2[k]);
        unsigned u = __float_as_uint(dist);
        u ^= ((unsigned)((int)u >> 31)) | 0x80000000u;  // monotone float->uint
        unsigned long long p = ((unsigned long long)u << 32) | (unsigned)k;
        best = (p < best) ? p : best;
    }
    atomicMin(&cand[row], best);
}

// ---------------- scatter: counts + segment sums via atomics ----------------
__global__ __launch_bounds__(256) void vq_scatter(const float* __restrict__ Z,
                                                  const unsigned long long* __restrict__ cand,
                                                  float* __restrict__ counts,
                                                  float* __restrict__ sums)
{
    int row = blockIdx.x * 256 + threadIdx.x;
    int k   = (int)(cand[row] & 0xffffffffu);
    atomicAdd(&counts[k], 1.0f);
    const float4* zp = reinterpret_cast<const float4*>(Z + (size_t)row * DD);
    float* srow = sums + (size_t)k * DD;
    for (int q = 0; q < 32; ++q) {
        float4 z = zp[q];
        atomicAdd(&srow[4 * q + 0], z.x);
        atomicAdd(&srow[4 * q + 1], z.y);
        atomicAdd(&srow[4 * q + 2], z.z);
        atomicAdd(&srow[4 * q + 3], z.w);
    }
}

// ---------------- update: c_new, w_new ----------------
__global__ __launch_bounds__(256) void vq_update(const float* __restrict__ Wd,
                                                 const float* __restrict__ dict_cnt,
                                                 const float* __restrict__ counts,
                                                 const float* __restrict__ sums,
                                                 float* __restrict__ w_new_out,
                                                 float* __restrict__ c_new_out)
{
    int t = blockIdx.x * 256 + threadIdx.x;   // 0 .. K*D-1
    int k = t >> 7;
    int d = t & 127;
    float cnt = dict_cnt[k];
    float ck  = counts[k];
    bool assigned = ck > 0.f;
    float cn = assigned
                 ? __fadd_rn(__fmul_rn(0.99f, cnt), __fmul_rn(0.01f, ck))
                 : cnt;
    float w  = Wd[t];
    float wn = w;
    if (assigned) {
        float num = __fmul_rn(0.01f, sums[t]);
        wn = __fadd_rn(__fmul_rn(0.99f, w), num / fmaxf(cn, 1e-12f));
    }
    w_new_out[t] = wn;
    if (d == 0) c_new_out[k] = cn;
}

// ---------------- gather: st_out = w_new[i], commit-loss partials ----------------
__global__ __launch_bounds__(256) void vq_gather(const float* __restrict__ Z,
                                                 const unsigned long long* __restrict__ cand,
                                                 const float* __restrict__ w_new,
                                                 float* __restrict__ st_out,
                                                 float* __restrict__ loss_bins)
{
    int wave = threadIdx.x >> 6;   // 0..3
    int lane = threadIdx.x & 63;
    int row  = blockIdx.x * 4 + wave;
    int k    = (int)(cand[row] & 0xffffffffu);

    const float2* zp = reinterpret_cast<const float2*>(Z + (size_t)row * DD);
    const float2* wp = reinterpret_cast<const float2*>(w_new + (size_t)k * DD);
    float2 z = zp[lane];
    float2 w = wp[lane];
    reinterpret_cast<float2*>(st_out + (size_t)row * DD)[lane] = w;

    float dx = z.x - w.x, dy = z.y - w.y;
    float part = fmaf(dx, dx, dy * dy);
#pragma unroll
    for (int off = 32; off; off >>= 1) part += __shfl_down(part, off, 64);

    __shared__ float sm[4];
    if (lane == 0) sm[wave] = part;
    __syncthreads();
    if (threadIdx.x == 0) {
        float s = (sm[0] + sm[1]) + (sm[2] + sm[3]);
        atomicAdd(&loss_bins[(blockIdx.x & 255) * 16], s);
    }
}

// ---------------- finish: loss = sum(bins)/N ----------------
__global__ void vq_finish(const float* __restrict__ loss_bins,
                          float* __restrict__ out_loss)
{
    if (threadIdx.x == 0) {
        float s = 0.f;
        for (int i = 0; i < 256; ++i) s += loss_bins[i * 16];
        out_loss[0] = s * (1.0f / 65536.0f);
    }
}

extern "C" void kernel_launch(void* const* d_in, const int* in_sizes, int n_in,
                              void* d_out, int out_size, void* d_ws, size_t ws_size,
                              hipStream_t stream)
{
    const float* Z        = (const float*)d_in[0];
    const float* Wd       = (const float*)d_in[1];
    const float* dict_cnt = (const float*)d_in[2];

    float* out      = (float*)d_out;
    float* st_out   = out;                          // 65536*128
    float* out_loss = out + (size_t)NN * DD;        // 1
    float* w_new    = out_loss + 1;                 // 2048*128
    float* c_new    = w_new + (size_t)KK * DD;      // 2048

    char* ws = (char*)d_ws;
    unsigned long long* cand = (unsigned long long*)ws;      // 65536*8 = 524288 B
    float* counts = (float*)(ws + 524288);                   // 8192 B
    float* sums   = (float*)(ws + 532480);                   // 1048576 B
    float* bins   = (float*)(ws + 1581056);                  // 256*64 B
    float* w2     = (float*)(ws + 1597440);                  // 8192 B

    hipMemsetAsync(cand, 0xFF, (size_t)NN * 8, stream);
    hipMemsetAsync(counts, 0, 8192 + 1048576 + 16384, stream);

    vq_prep_w<<<8, 256, 0, stream>>>(Wd, w2);
    dim3 ag(NN / 64, 4);
    vq_assign<<<ag, 64, 0, stream>>>(Z, Wd, w2, cand);
    vq_scatter<<<NN / 256, 256, 0, stream>>>(Z, cand, counts, sums);
    vq_update<<<(KK * DD) / 256, 256, 0, stream>>>(Wd, dict_cnt, counts, sums, w_new, c_new);
    vq_gather<<<NN / 4, 256, 0, stream>>>(Z, cand, w_new, st_out, bins);
    vq_finish<<<1, 64, 0, stream>>>(bins, out_loss);
}

// Round 2
// 308.412 us; speedup vs baseline: 5.5013x; 5.5013x over previous
//
#include <hip/hip_runtime.h>
#include <hip/hip_bf16.h>

#define NN 65536
#define KK 2048
#define DD 128

typedef __attribute__((ext_vector_type(8))) short bf16x8;
typedef __attribute__((ext_vector_type(4))) float f32x4;

static __device__ __forceinline__ unsigned short f2bf(float f) {
    unsigned u = __float_as_uint(f);
    unsigned r = u + 0x7fffu + ((u >> 16) & 1u);   // RTN-even
    return (unsigned short)(r >> 16);
}
static __device__ __forceinline__ float bf2f(unsigned short b) {
    return __uint_as_float(((unsigned)b) << 16);
}
static __device__ __forceinline__ unsigned encf(float f) {
    unsigned u = __float_as_uint(f);
    return u ^ (((unsigned)((int)u >> 31)) | 0x80000000u);   // monotone float->uint
}
static __device__ __forceinline__ float decf(unsigned u) {
    return (u & 0x80000000u) ? __uint_as_float(u ^ 0x80000000u) : __uint_as_float(~u);
}

static __device__ __forceinline__ void gll16(const void* g, void* l) {
    __builtin_amdgcn_global_load_lds(
        (const __attribute__((address_space(1))) void*)g,
        (__attribute__((address_space(3))) void*)l, 16, 0, 0);
}

// ---- split fp32 rows into bf16 hi/lo tiles, layout [rb][tile][g][row][8] ----
// tile t in 0..3 = hi part of k 32t..32t+31 ; tile 4..7 = lo part.
__global__ __launch_bounds__(256) void vq_split(const float* __restrict__ src,
                                                short* __restrict__ dst)
{
    int tid = threadIdx.x;
    int rl = tid >> 4, c = tid & 15;          // 16 rows x 16 chunks of 8
    int row = blockIdx.x * 16 + rl;
    int rb = row >> 7, rr = row & 127;
    const float4* zp = reinterpret_cast<const float4*>(src + (size_t)row * DD + c * 8);
    float4 v0 = zp[0], v1 = zp[1];
    float v[8] = {v0.x, v0.y, v0.z, v0.w, v1.x, v1.y, v1.z, v1.w};
    bf16x8 hv, lv;
#pragma unroll
    for (int j = 0; j < 8; ++j) {
        unsigned short h = f2bf(v[j]);
        hv[j] = (short)h;
        lv[j] = (short)f2bf(v[j] - bf2f(h));
    }
    int ts = c >> 2, g = c & 3;
    size_t bhi = (((size_t)rb * 8 + ts) * 4096) + g * 1024 + rr * 8;
    *reinterpret_cast<bf16x8*>(dst + bhi) = hv;
    *reinterpret_cast<bf16x8*>(dst + bhi + 4 * 4096) = lv;
}

// ---- row squared-norms, 4-chain fmaf order (bit-matches round-1) ----
__global__ __launch_bounds__(256) void vq_rowsq(const float* __restrict__ src,
                                                float* __restrict__ out)
{
    int r = blockIdx.x * 256 + threadIdx.x;
    const float4* p = reinterpret_cast<const float4*>(src + (size_t)r * DD);
    float s0 = 0.f, s1 = 0.f, s2 = 0.f, s3 = 0.f;
#pragma unroll
    for (int q = 0; q < 32; ++q) {
        float4 w = p[q];
        s0 = fmaf(w.x, w.x, s0);
        s1 = fmaf(w.y, w.y, s1);
        s2 = fmaf(w.z, w.z, s2);
        s3 = fmaf(w.w, w.w, s3);
    }
    out[r] = (s0 + s1) + (s2 + s3);
}

// ---- MFMA distance GEMM + per-(row, colblock) top-2 candidate emit ----
// S = Zhi.Whi^T + Zhi.Wlo^T + Zlo.Whi^T over 12 k-tiles of 32.
__global__ __launch_bounds__(256) void vq_gemm(const short* __restrict__ Zre,
                                               const short* __restrict__ Wre,
                                               const float* __restrict__ w2,
                                               unsigned long long* __restrict__ top2)
{
    int rb = blockIdx.x, cb = blockIdx.y;
    int tid = threadIdx.x;
    int wid = tid >> 6, lane = tid & 63;
    int wr = wid >> 1, wc = wid & 1;

    __shared__ short As[4096];   // [g][row][8] for current k-tile
    __shared__ short Bs[4096];
    char* Ac = (char*)As;
    char* Bc = (char*)Bs;

    f32x4 acc[4][4] = {};
    const short* zbase = Zre + (size_t)rb * 8 * 4096;
    const short* wbase = Wre + (size_t)cb * 8 * 4096;

    int g = lane >> 4;
    int l15 = lane & 15;

    for (int t = 0; t < 12; ++t) {
        int tsA = (t < 4) ? t : t - 4;   // hi,hi,lo
        int tsB = (t < 8) ? t : t - 8;   // hi,lo,hi
        const short* ga = zbase + tsA * 4096;
        const short* gb = wbase + tsB * 4096;
        __syncthreads();
        gll16(ga + tid * 8, Ac + tid * 16);
        gll16(ga + 2048 + tid * 8, Ac + 4096 + tid * 16);
        gll16(gb + tid * 8, Bc + tid * 16);
        gll16(gb + 2048 + tid * 8, Bc + 4096 + tid * 16);
        __syncthreads();

        bf16x8 a[4], b[4];
#pragma unroll
        for (int m = 0; m < 4; ++m)
            a[m] = *reinterpret_cast<const bf16x8*>(As + g * 1024 + (wr * 64 + m * 16 + l15) * 8);
#pragma unroll
        for (int n = 0; n < 4; ++n)
            b[n] = *reinterpret_cast<const bf16x8*>(Bs + g * 1024 + (wc * 64 + n * 16 + l15) * 8);
#pragma unroll
        for (int m = 0; m < 4; ++m)
#pragma unroll
            for (int n = 0; n < 4; ++n)
                acc[m][n] = __builtin_amdgcn_mfma_f32_16x16x32_bf16(a[m], b[n], acc[m][n], 0, 0, 0);
    }

    // epilogue: dist' = w2[c] - 2 s ; per-row top-2 over this block's 128 cols
    int cg0 = cb * 128 + wc * 64 + l15;
    float w2v[4];
#pragma unroll
    for (int n = 0; n < 4; ++n) w2v[n] = w2[cg0 + n * 16];

#pragma unroll
    for (int m = 0; m < 4; ++m) {
#pragma unroll
        for (int r = 0; r < 4; ++r) {
            unsigned long long k1 = ~0ull, k2 = ~0ull;
#pragma unroll
            for (int n = 0; n < 4; ++n) {
                float d = fmaf(-2.0f, acc[m][n][r], w2v[n]);
                unsigned long long key =
                    (((unsigned long long)encf(d)) << 32) | (unsigned)(cg0 + n * 16);
                if (key < k1) { k2 = k1; k1 = key; }
                else if (key < k2) { k2 = key; }
            }
#pragma unroll
            for (int msk = 1; msk < 16; msk <<= 1) {
                unsigned long long o1 = __shfl_xor(k1, msk);
                unsigned long long o2 = __shfl_xor(k2, msk);
                unsigned long long hi1 = (k1 > o1) ? k1 : o1;
                unsigned long long lo2 = (k2 < o2) ? k2 : o2;
                k1 = (k1 < o1) ? k1 : o1;
                k2 = (hi1 < lo2) ? hi1 : lo2;
            }
            if (l15 == 0) {
                int row = rb * 128 + wr * 64 + m * 16 + (lane >> 4) * 4 + r;
                unsigned long long* dst = top2 + ((size_t)row * 16 + cb) * 2;
                dst[0] = k1;
                dst[1] = k2;
            }
        }
    }
}

// ---- resolve: global best from 32 candidates; exact fp32 re-score if close ----
__global__ __launch_bounds__(256) void vq_resolve(const unsigned long long* __restrict__ top2,
                                                  const float* __restrict__ Z,
                                                  const float* __restrict__ Wd,
                                                  const float* __restrict__ z2,
                                                  const float* __restrict__ w2,
                                                  int* __restrict__ assign)
{
    int row = blockIdx.x * 256 + threadIdx.x;
    const unsigned long long* tp = top2 + (size_t)row * 32;
    unsigned long long loc[32];
    unsigned long long best = ~0ull;
#pragma unroll
    for (int i = 0; i < 32; ++i) {
        loc[i] = tp[i];
        if (loc[i] < best) best = loc[i];
    }
    float dbest = decf((unsigned)(best >> 32));
    float lim = dbest + 2e-4f;
    int cols[8];
    int nc = 0;
#pragma unroll
    for (int i = 0; i < 32; ++i) {
        if (decf((unsigned)(loc[i] >> 32)) <= lim) {
            if (nc < 8) cols[nc] = (int)(loc[i] & 0xffffffffu);
            ++nc;
        }
    }
    int res = (int)(best & 0xffffffffu);
    if (nc > 1) {
        // exact re-score, bit-identical to the verified round-1 formula
        const float4* zp = reinterpret_cast<const float4*>(Z + (size_t)row * DD);
        float z2v = z2[row];
        unsigned long long be = ~0ull;
        int lim_n = nc < 8 ? nc : 8;
        for (int i = 0; i < lim_n; ++i) {
            int k = cols[i];
            const float4* wp = reinterpret_cast<const float4*>(Wd + (size_t)k * DD);
            float a0 = 0.f, a1 = 0.f, a2 = 0.f, a3 = 0.f;
#pragma unroll
            for (int q = 0; q < 32; ++q) {
                float4 zq = zp[q];
                float4 wq = wp[q];
                a0 = fmaf(zq.x, wq.x, a0);
                a1 = fmaf(zq.y, wq.y, a1);
                a2 = fmaf(zq.z, wq.z, a2);
                a3 = fmaf(zq.w, wq.w, a3);
            }
            float s = (a0 + a1) + (a2 + a3);
            float t = __fsub_rn(z2v, __fmul_rn(2.0f, s));
            float dist = __fadd_rn(t, w2[k]);
            unsigned long long key = (((unsigned long long)encf(dist)) << 32) | (unsigned)k;
            if (key < be) be = key;
        }
        res = (int)(be & 0xffffffffu);
    }
    assign[row] = res;
}

// ---- scatter: 1 element-atomic per thread, coalesced ----
__global__ __launch_bounds__(256) void vq_scatter(const float* __restrict__ Z,
                                                  const int* __restrict__ assign,
                                                  float* __restrict__ counts,
                                                  float* __restrict__ sums)
{
    int t = blockIdx.x * 256 + threadIdx.x;   // 0 .. N*D-1
    int row = t >> 7, d = t & 127;
    int k = assign[row];
    atomicAdd(&sums[(size_t)k * DD + d], Z[t]);
    if (d == 0) atomicAdd(&counts[k], 1.0f);
}

// ---- update: c_new, w_new ----
__global__ __launch_bounds__(256) void vq_update(const float* __restrict__ Wd,
                                                 const float* __restrict__ dict_cnt,
                                                 const float* __restrict__ counts,
                                                 const float* __restrict__ sums,
                                                 float* __restrict__ w_new_out,
                                                 float* __restrict__ c_new_out)
{
    int t = blockIdx.x * 256 + threadIdx.x;
    int k = t >> 7, d = t & 127;
    float cnt = dict_cnt[k];
    float ck = counts[k];
    bool assigned = ck > 0.f;
    float cn = assigned ? __fadd_rn(__fmul_rn(0.99f, cnt), __fmul_rn(0.01f, ck)) : cnt;
    float w = Wd[t];
    float wn = w;
    if (assigned) {
        float num = __fmul_rn(0.01f, sums[t]);
        wn = __fadd_rn(__fmul_rn(0.99f, w), num / fmaxf(cn, 1e-12f));
    }
    w_new_out[t] = wn;
    if (d == 0) c_new_out[k] = cn;
}

// ---- gather: st_out = w_new[i]; commit-loss partials ----
__global__ __launch_bounds__(256) void vq_gather(const float* __restrict__ Z,
                                                 const int* __restrict__ assign,
                                                 const float* __restrict__ w_new,
                                                 float* __restrict__ st_out,
                                                 float* __restrict__ loss_bins)
{
    int wave = threadIdx.x >> 6;
    int lane = threadIdx.x & 63;
    int row = blockIdx.x * 4 + wave;
    int k = assign[row];

    const float2* zp = reinterpret_cast<const float2*>(Z + (size_t)row * DD);
    const float2* wp = reinterpret_cast<const float2*>(w_new + (size_t)k * DD);
    float2 z = zp[lane];
    float2 w = wp[lane];
    reinterpret_cast<float2*>(st_out + (size_t)row * DD)[lane] = w;

    float dx = z.x - w.x, dy = z.y - w.y;
    float part = fmaf(dx, dx, dy * dy);
#pragma unroll
    for (int off = 32; off; off >>= 1) part += __shfl_down(part, off, 64);

    __shared__ float sm[4];
    if (lane == 0) sm[wave] = part;
    __syncthreads();
    if (threadIdx.x == 0) {
        float s = (sm[0] + sm[1]) + (sm[2] + sm[3]);
        atomicAdd(&loss_bins[(blockIdx.x & 255) * 16], s);
    }
}

__global__ void vq_finish(const float* __restrict__ loss_bins,
                          float* __restrict__ out_loss)
{
    if (threadIdx.x == 0) {
        float s = 0.f;
        for (int i = 0; i < 256; ++i) s += loss_bins[i * 16];
        out_loss[0] = s * (1.0f / 65536.0f);
    }
}

extern "C" void kernel_launch(void* const* d_in, const int* in_sizes, int n_in,
                              void* d_out, int out_size, void* d_ws, size_t ws_size,
                              hipStream_t stream)
{
    const float* Z        = (const float*)d_in[0];
    const float* Wd       = (const float*)d_in[1];
    const float* dict_cnt = (const float*)d_in[2];

    float* out      = (float*)d_out;
    float* st_out   = out;
    float* out_loss = out + (size_t)NN * DD;
    float* w_new    = out_loss + 1;
    float* c_new    = w_new + (size_t)KK * DD;

    // ws: Zre (33.5 MB) + assign + bins + w2
    char* ws = (char*)d_ws;
    short* Zre  = (short*)ws;                         // 33,554,432 B
    int* assign = (int*)(ws + 33554432);              // 262,144 B
    float* bins = (float*)(ws + 33816576);            // 16,384 B
    float* w2   = (float*)(ws + 33832960);            // 8,192 B

    // transient scratch inside the st_out region of d_out (dead before vq_gather)
    char* sc = (char*)d_out;
    unsigned long long* top2 = (unsigned long long*)sc;   // 16,777,216 B
    short* Wre   = (short*)(sc + 16777216);               // 1,048,576 B
    float* counts = (float*)(sc + 17825792);              // 8,192 B
    float* sums   = (float*)(sc + 17833984);              // 1,048,576 B
    float* z2     = (float*)(sc + 18882560);              // 262,144 B

    hipMemsetAsync(counts, 0, 8192 + 1048576, stream);
    hipMemsetAsync(bins, 0, 16384, stream);

    vq_split<<<NN / 16, 256, 0, stream>>>(Z, Zre);
    vq_split<<<KK / 16, 256, 0, stream>>>(Wd, Wre);
    vq_rowsq<<<NN / 256, 256, 0, stream>>>(Z, z2);
    vq_rowsq<<<KK / 256, 256, 0, stream>>>(Wd, w2);

    dim3 gg(NN / 128, KK / 128);
    vq_gemm<<<gg, 256, 0, stream>>>(Zre, Wre, w2, top2);
    vq_resolve<<<NN / 256, 256, 0, stream>>>(top2, Z, Wd, z2, w2, assign);
    vq_scatter<<<(NN * DD) / 256, 256, 0, stream>>>(Z, assign, counts, sums);
    vq_update<<<(KK * DD) / 256, 256, 0, stream>>>(Wd, dict_cnt, counts, sums, w_new, c_new);
    vq_gather<<<NN / 4, 256, 0, stream>>>(Z, assign, w_new, st_out, bins);
    vq_finish<<<1, 64, 0, stream>>>(bins, out_loss);
}

// Round 3
// 152.823 us; speedup vs baseline: 11.1023x; 2.0181x over previous
//
#include <hip/hip_runtime.h>
#include <hip/hip_bf16.h>

#define NN 65536
#define KK 2048
#define DD 128

typedef __attribute__((ext_vector_type(8))) _Float16 f16x8;
typedef __attribute__((ext_vector_type(4))) float f32x4;

static __device__ __forceinline__ unsigned encf(float f) {
    unsigned u = __float_as_uint(f);
    return u ^ (((unsigned)((int)u >> 31)) | 0x80000000u);   // monotone float->uint
}

static __device__ __forceinline__ void gll16(const void* g, void* l) {
    __builtin_amdgcn_global_load_lds(
        (const __attribute__((address_space(1))) void*)g,
        (__attribute__((address_space(3))) void*)l, 16, 0, 0);
}

// ---- split fp32 rows into fp16 fragment-ordered tiles ----
// layout: [rowblock rb][ktile t:4][kgroup g:4][row 128][8]  (halfs)
__global__ __launch_bounds__(256) void vq_split(const float* __restrict__ src,
                                                _Float16* __restrict__ dst,
                                                float scale)
{
    int tid = threadIdx.x;
    int rl = tid >> 4, c = tid & 15;          // 16 rows x 16 chunks of 8
    int row = blockIdx.x * 16 + rl;
    int rb = row >> 7, rr = row & 127;
    const float4* zp = reinterpret_cast<const float4*>(src + (size_t)row * DD + c * 8);
    float4 v0 = zp[0], v1 = zp[1];
    float v[8] = {v0.x, v0.y, v0.z, v0.w, v1.x, v1.y, v1.z, v1.w};
    f16x8 hv;
#pragma unroll
    for (int j = 0; j < 8; ++j) hv[j] = (_Float16)(v[j] * scale);
    int ts = c >> 2, g = c & 3;
    size_t off = (((size_t)rb * 4 + ts) * 4 + g) * 1024 + (size_t)rr * 8;
    *reinterpret_cast<f16x8*>(dst + off) = hv;
}

// ---- w2[k] = sum(W[k]^2), 4-chain fmaf ----
__global__ __launch_bounds__(256) void vq_w2(const float* __restrict__ Wd,
                                             float* __restrict__ w2)
{
    int k = blockIdx.x * 256 + threadIdx.x;
    const float4* wp = reinterpret_cast<const float4*>(Wd + (size_t)k * DD);
    float s0 = 0.f, s1 = 0.f, s2 = 0.f, s3 = 0.f;
#pragma unroll
    for (int q = 0; q < 32; ++q) {
        float4 w = wp[q];
        s0 = fmaf(w.x, w.x, s0);
        s1 = fmaf(w.y, w.y, s1);
        s2 = fmaf(w.z, w.z, s2);
        s3 = fmaf(w.w, w.w, s3);
    }
    w2[k] = (s0 + s1) + (s2 + s3);
}

// ---- MFMA distance GEMM: 128 rows x all 2048 cols per block ----
// A frags in registers (loaded once); B double-buffered in LDS via gll16.
// Emits per-row top-2 (per 64-col wave half) as index-clobbered floats.
__global__ __launch_bounds__(256, 2) void vq_gemm(const _Float16* __restrict__ Zre,
                                                  const _Float16* __restrict__ Wre,
                                                  const float* __restrict__ w2,
                                                  float* __restrict__ top2)
{
    int rb  = blockIdx.x;
    int tid = threadIdx.x;
    int wid = tid >> 6, lane = tid & 63;
    int wr = wid >> 1, wc = wid & 1;
    int g = lane >> 4, l15 = lane & 15;

    __shared__ _Float16 Bs[2][16384];   // 2 x 32KB

    // A fragments for this wave's 64 rows x 128 k: 16 x f16x8 = 64 VGPR
    const _Float16* zb = Zre + (size_t)rb * 16384;
    f16x8 a[4][4];
#pragma unroll
    for (int t = 0; t < 4; ++t)
#pragma unroll
        for (int m = 0; m < 4; ++m)
            a[t][m] = *reinterpret_cast<const f16x8*>(
                zb + (t * 4 + g) * 1024 + (wr * 64 + m * 16 + l15) * 8);

    const float INF = __uint_as_float(0x7F800000u);
    float b1[16], b2[16];
#pragma unroll
    for (int s = 0; s < 16; ++s) { b1[s] = INF; b2[s] = INF; }

    const f32x4 zz = {0.f, 0.f, 0.f, 0.f};

    // prologue: stage cb=0 into buf 0
#pragma unroll
    for (int j = 0; j < 8; ++j)
        gll16(Wre + (size_t)j * 2048 + tid * 8, &Bs[0][j * 2048 + tid * 8]);
    __syncthreads();

    int cur = 0;
    for (int cb = 0; cb < 16; ++cb) {
        if (cb < 15) {
            const _Float16* wb = Wre + (size_t)(cb + 1) * 16384;
#pragma unroll
            for (int j = 0; j < 8; ++j)
                gll16(wb + (size_t)j * 2048 + tid * 8, &Bs[cur ^ 1][j * 2048 + tid * 8]);
        }

        const _Float16* bb = Bs[cur];
        f32x4 acc[4][4];
#pragma unroll
        for (int t = 0; t < 4; ++t) {
            f16x8 b[4];
#pragma unroll
            for (int n = 0; n < 4; ++n)
                b[n] = *reinterpret_cast<const f16x8*>(
                    bb + (t * 4 + g) * 1024 + (wc * 64 + n * 16 + l15) * 8);
#pragma unroll
            for (int m = 0; m < 4; ++m)
#pragma unroll
                for (int n = 0; n < 4; ++n)
                    acc[m][n] = __builtin_amdgcn_mfma_f32_16x16x32_f16(
                        a[t][m], b[n], (t == 0) ? zz : acc[m][n], 0, 0, 0);
        }

        // epilogue: d = w2 - 2*z.w  (acc holds z.(128w) -> scale -2/128)
        int cg0 = cb * 128 + wc * 64 + l15;
        float w2v[4];
#pragma unroll
        for (int n = 0; n < 4; ++n) w2v[n] = w2[cg0 + n * 16];
#pragma unroll
        for (int m = 0; m < 4; ++m)
#pragma unroll
            for (int n = 0; n < 4; ++n)
#pragma unroll
                for (int r = 0; r < 4; ++r) {
                    float d = fmaf(-0.015625f, acc[m][n][r], w2v[n]);
                    unsigned ub = (__float_as_uint(d) & 0xFFFFF800u)
                                  | (unsigned)(cg0 + n * 16);
                    float df = __uint_as_float(ub);
                    int s = m * 4 + r;
                    b2[s] = fminf(b2[s], fmaxf(df, b1[s]));
                    b1[s] = fminf(b1[s], df);
                }

        __syncthreads();
        cur ^= 1;
    }

    // final cross-lane merge (within 16-lane col groups), once per block
#pragma unroll
    for (int s = 0; s < 16; ++s) {
        float v1 = b1[s], v2 = b2[s];
#pragma unroll
        for (int msk = 1; msk < 16; msk <<= 1) {
            float o1 = __shfl_xor(v1, msk, 64);
            float o2 = __shfl_xor(v2, msk, 64);
            float hi = fmaxf(v1, o1);
            v1 = fminf(v1, o1);
            v2 = fminf(fminf(v2, o2), hi);
        }
        if (l15 == 0) {
            int row = rb * 128 + wr * 64 + (s >> 2) * 16 + g * 4 + (s & 3);
            top2[(size_t)row * 4 + wc * 2 + 0] = v1;
            top2[(size_t)row * 4 + wc * 2 + 1] = v2;
        }
    }
}

// ---- resolve: pick best of 4 candidates; exact fp32 re-score if within delta ----
__global__ __launch_bounds__(256) void vq_resolve(const float* __restrict__ top2,
                                                  const float* __restrict__ Z,
                                                  const float* __restrict__ Wd,
                                                  const float* __restrict__ w2,
                                                  int* __restrict__ assign)
{
    int row = blockIdx.x * 256 + threadIdx.x;
    float4 t4 = *reinterpret_cast<const float4*>(top2 + (size_t)row * 4);
    float vv[4] = {t4.x, t4.y, t4.z, t4.w};
    float dv[4];
    int dc[4];
#pragma unroll
    for (int i = 0; i < 4; ++i) {
        unsigned b = __float_as_uint(vv[i]);
        dc[i] = (int)(b & 2047u);
        dv[i] = __uint_as_float(b & 0xFFFFF800u);
    }
    int ib = 0;
#pragma unroll
    for (int i = 1; i < 4; ++i)
        if (dv[i] < dv[ib]) ib = i;
    float lim = dv[ib] + 6e-4f;
    int cols[4];
    int nc = 0;
#pragma unroll
    for (int i = 0; i < 4; ++i)
        if (dv[i] <= lim) cols[nc++] = dc[i];

    int res = dc[ib];
    if (nc > 1) {
        const float4* zp = reinterpret_cast<const float4*>(Z + (size_t)row * DD);
        float s0 = 0.f, s1 = 0.f, s2 = 0.f, s3 = 0.f;
        for (int q = 0; q < 32; ++q) {
            float4 z = zp[q];
            s0 = fmaf(z.x, z.x, s0);
            s1 = fmaf(z.y, z.y, s1);
            s2 = fmaf(z.z, z.z, s2);
            s3 = fmaf(z.w, z.w, s3);
        }
        float z2v = (s0 + s1) + (s2 + s3);
        unsigned long long be = ~0ull;
        for (int i = 0; i < nc; ++i) {
            int k = cols[i];
            const float4* wp = reinterpret_cast<const float4*>(Wd + (size_t)k * DD);
            float a0 = 0.f, a1 = 0.f, a2 = 0.f, a3 = 0.f;
            for (int q = 0; q < 32; ++q) {
                float4 zq = zp[q];
                float4 wq = wp[q];
                a0 = fmaf(zq.x, wq.x, a0);
                a1 = fmaf(zq.y, wq.y, a1);
                a2 = fmaf(zq.z, wq.z, a2);
                a3 = fmaf(zq.w, wq.w, a3);
            }
            float sdot = (a0 + a1) + (a2 + a3);
            float t = __fsub_rn(z2v, __fmul_rn(2.0f, sdot));
            float dist = __fadd_rn(t, w2[k]);
            unsigned long long key = (((unsigned long long)encf(dist)) << 32) | (unsigned)k;
            if (key < be) be = key;
        }
        res = (int)(be & 0xffffffffu);
    }
    assign[row] = res;
}

// ---- scatter: 1 element-atomic per thread, coalesced ----
__global__ __launch_bounds__(256) void vq_scatter(const float* __restrict__ Z,
                                                  const int* __restrict__ assign,
                                                  float* __restrict__ counts,
                                                  float* __restrict__ sums)
{
    int t = blockIdx.x * 256 + threadIdx.x;   // 0 .. N*D-1
    int row = t >> 7, d = t & 127;
    int k = assign[row];
    atomicAdd(&sums[(size_t)k * DD + d], Z[t]);
    if (d == 0) atomicAdd(&counts[k], 1.0f);
}

// ---- update: c_new, w_new ----
__global__ __launch_bounds__(256) void vq_update(const float* __restrict__ Wd,
                                                 const float* __restrict__ dict_cnt,
                                                 const float* __restrict__ counts,
                                                 const float* __restrict__ sums,
                                                 float* __restrict__ w_new_out,
                                                 float* __restrict__ c_new_out)
{
    int t = blockIdx.x * 256 + threadIdx.x;
    int k = t >> 7, d = t & 127;
    float cnt = dict_cnt[k];
    float ck = counts[k];
    bool assigned = ck > 0.f;
    float cn = assigned ? __fadd_rn(__fmul_rn(0.99f, cnt), __fmul_rn(0.01f, ck)) : cnt;
    float w = Wd[t];
    float wn = w;
    if (assigned) {
        float num = __fmul_rn(0.01f, sums[t]);
        wn = __fadd_rn(__fmul_rn(0.99f, w), num / fmaxf(cn, 1e-12f));
    }
    w_new_out[t] = wn;
    if (d == 0) c_new_out[k] = cn;
}

// ---- gather: st_out = w_new[i]; commit-loss partials ----
__global__ __launch_bounds__(256) void vq_gather(const float* __restrict__ Z,
                                                 const int* __restrict__ assign,
                                                 const float* __restrict__ w_new,
                                                 float* __restrict__ st_out,
                                                 float* __restrict__ loss_bins)
{
    int wave = threadIdx.x >> 6;
    int lane = threadIdx.x & 63;
    int row = blockIdx.x * 4 + wave;
    int k = assign[row];

    const float2* zp = reinterpret_cast<const float2*>(Z + (size_t)row * DD);
    const float2* wp = reinterpret_cast<const float2*>(w_new + (size_t)k * DD);
    float2 z = zp[lane];
    float2 w = wp[lane];
    reinterpret_cast<float2*>(st_out + (size_t)row * DD)[lane] = w;

    float dx = z.x - w.x, dy = z.y - w.y;
    float part = fmaf(dx, dx, dy * dy);
#pragma unroll
    for (int off = 32; off; off >>= 1) part += __shfl_down(part, off, 64);

    __shared__ float sm[4];
    if (lane == 0) sm[wave] = part;
    __syncthreads();
    if (threadIdx.x == 0) {
        float s = (sm[0] + sm[1]) + (sm[2] + sm[3]);
        atomicAdd(&loss_bins[(blockIdx.x & 255) * 16], s);
    }
}

__global__ void vq_finish(const float* __restrict__ loss_bins,
                          float* __restrict__ out_loss)
{
    if (threadIdx.x == 0) {
        float s = 0.f;
        for (int i = 0; i < 256; ++i) s += loss_bins[i * 16];
        out_loss[0] = s * (1.0f / 65536.0f);
    }
}

extern "C" void kernel_launch(void* const* d_in, const int* in_sizes, int n_in,
                              void* d_out, int out_size, void* d_ws, size_t ws_size,
                              hipStream_t stream)
{
    const float* Z        = (const float*)d_in[0];
    const float* Wd       = (const float*)d_in[1];
    const float* dict_cnt = (const float*)d_in[2];

    float* out      = (float*)d_out;
    float* st_out   = out;
    float* out_loss = out + (size_t)NN * DD;
    float* w_new    = out_loss + 1;
    float* c_new    = w_new + (size_t)KK * DD;

    char* ws = (char*)d_ws;
    _Float16* Zre = (_Float16*)ws;                       // 16,777,216 B
    _Float16* Wre = (_Float16*)(ws + 16777216);          //    524,288 B
    float* w2     = (float*)(ws + 17301504);             //      8,192 B
    float* top2   = (float*)(ws + 17309696);             //  1,048,576 B
    int* assign   = (int*)(ws + 18358272);               //    262,144 B
    float* counts = (float*)(ws + 18620416);             //      8,192 B
    float* sums   = (float*)(ws + 18628608);             //  1,048,576 B
    float* bins   = (float*)(ws + 19677184);             //     16,384 B

    hipMemsetAsync(counts, 0, 8192 + 1048576, stream);
    hipMemsetAsync(bins, 0, 16384, stream);

    vq_split<<<NN / 16, 256, 0, stream>>>(Z, Zre, 1.0f);
    vq_split<<<KK / 16, 256, 0, stream>>>(Wd, Wre, 128.0f);
    vq_w2<<<KK / 256, 256, 0, stream>>>(Wd, w2);

    vq_gemm<<<NN / 128, 256, 0, stream>>>(Zre, Wre, w2, top2);
    vq_resolve<<<NN / 256, 256, 0, stream>>>(top2, Z, Wd, w2, assign);
    vq_scatter<<<(NN * DD) / 256, 256, 0, stream>>>(Z, assign, counts, sums);
    vq_update<<<(KK * DD) / 256, 256, 0, stream>>>(Wd, dict_cnt, counts, sums, w_new, c_new);
    vq_gather<<<NN / 4, 256, 0, stream>>>(Z, assign, w_new, st_out, bins);
    vq_finish<<<1, 64, 0, stream>>>(bins, out_loss);
}

// Round 4
// 145.937 us; speedup vs baseline: 11.6261x; 1.0472x over previous
//
#include <hip/hip_runtime.h>
#include <hip/hip_bf16.h>

#define NN 65536
#define KK 2048
#define DD 128

typedef __attribute__((ext_vector_type(8))) _Float16 f16x8;
typedef __attribute__((ext_vector_type(4))) float f32x4;

static __device__ __forceinline__ unsigned encf(float f) {
    unsigned u = __float_as_uint(f);
    return u ^ (((unsigned)((int)u >> 31)) | 0x80000000u);   // monotone float->uint
}

static __device__ __forceinline__ void gll16(const void* g, void* l) {
    __builtin_amdgcn_global_load_lds(
        (const __attribute__((address_space(1))) void*)g,
        (__attribute__((address_space(3))) void*)l, 16, 0, 0);
}

// ---- fused prep: Z->f16 frags, W->f16 frags (x128), w2 ----
// frag layout (both): [blk64 b][ktile t:4][kgroup g:4][row 64][8] halfs
__global__ __launch_bounds__(256) void vq_prep(const float* __restrict__ Z,
                                               const float* __restrict__ Wd,
                                               _Float16* __restrict__ Zre,
                                               _Float16* __restrict__ Wre,
                                               float* __restrict__ w2)
{
    int tid = threadIdx.x;
    int rl = tid >> 4, c = tid & 15;          // 16 rows x 16 chunks of 8
    int row = blockIdx.x * 16 + rl;
    bool isW = row >= NN;
    int r = isW ? row - NN : row;
    const float* src = isW ? Wd : Z;

    const float4* zp = reinterpret_cast<const float4*>(src + (size_t)r * DD + c * 8);
    float4 v0 = zp[0], v1 = zp[1];
    float v[8] = {v0.x, v0.y, v0.z, v0.w, v1.x, v1.y, v1.z, v1.w};

    float scale = isW ? 128.0f : 1.0f;
    f16x8 hv;
#pragma unroll
    for (int j = 0; j < 8; ++j) hv[j] = (_Float16)(v[j] * scale);

    int ts = c >> 2, g = c & 3;
    size_t off = (((size_t)(r >> 6) * 4 + ts) * 4 + g) * 512 + (size_t)(r & 63) * 8;
    _Float16* dst = isW ? Wre : Zre;
    *reinterpret_cast<f16x8*>(dst + off) = hv;

    if (isW) {
        float p = 0.f;
#pragma unroll
        for (int j = 0; j < 8; ++j) p = fmaf(v[j], v[j], p);
#pragma unroll
        for (int off2 = 1; off2 < 16; off2 <<= 1) p += __shfl_xor(p, off2, 64);
        if (c == 0) w2[r] = p;
    }
}

// ---- MFMA distance GEMM: 64 rows x 2048 cols per block, 64-col LDS tiles ----
__global__ __launch_bounds__(256, 4) void vq_gemm(const _Float16* __restrict__ Zre,
                                                  const _Float16* __restrict__ Wre,
                                                  const float* __restrict__ w2,
                                                  float* __restrict__ top2)
{
    int rb  = blockIdx.x;
    int tid = threadIdx.x;
    int wid = tid >> 6, lane = tid & 63;
    int wr = wid >> 1, wc = wid & 1;          // wave tile 32r x 32c
    int g = lane >> 4, l15 = lane & 15;

    __shared__ _Float16 Bs[2][8192];          // 2 x 16KB

    // A fragments: 32 rows x 128 k per wave-row-half -> 8 x f16x8 = 32 VGPR
    const _Float16* zb = Zre + (size_t)rb * 8192;
    f16x8 a[4][2];
#pragma unroll
    for (int t = 0; t < 4; ++t)
#pragma unroll
        for (int m = 0; m < 2; ++m)
            a[t][m] = *reinterpret_cast<const f16x8*>(
                zb + ((t * 4 + g) * 512 + (wr * 32 + m * 16 + l15) * 8));

    const float INF = __uint_as_float(0x7F800000u);
    float b1[8], b2[8];
#pragma unroll
    for (int s = 0; s < 8; ++s) { b1[s] = INF; b2[s] = INF; }

    const f32x4 zz = {0.f, 0.f, 0.f, 0.f};

    // prologue: stage cb=0
#pragma unroll
    for (int j = 0; j < 4; ++j)
        gll16(Wre + j * 2048 + tid * 8, &Bs[0][j * 2048 + tid * 8]);
    __syncthreads();

    int cur = 0;
    for (int cb = 0; cb < 32; ++cb) {
        if (cb < 31) {
            const _Float16* wb = Wre + (size_t)(cb + 1) * 8192;
#pragma unroll
            for (int j = 0; j < 4; ++j)
                gll16(wb + j * 2048 + tid * 8, &Bs[cur ^ 1][j * 2048 + tid * 8]);
        }

        const _Float16* bb = Bs[cur];
        f32x4 acc[2][2];
#pragma unroll
        for (int t = 0; t < 4; ++t) {
            f16x8 b[2];
#pragma unroll
            for (int n = 0; n < 2; ++n)
                b[n] = *reinterpret_cast<const f16x8*>(
                    bb + ((t * 4 + g) * 512 + (wc * 32 + n * 16 + l15) * 8));
#pragma unroll
            for (int m = 0; m < 2; ++m)
#pragma unroll
                for (int n = 0; n < 2; ++n)
                    acc[m][n] = __builtin_amdgcn_mfma_f32_16x16x32_f16(
                        a[t][m], b[n], (t == 0) ? zz : acc[m][n], 0, 0, 0);
        }

        // epilogue: d = w2 - 2 z.w  (acc = 128 z.w -> scale -1/64); 4 VALU/value
        int cg0 = cb * 64 + wc * 32 + l15;
        float w2v[2] = {w2[cg0], w2[cg0 + 16]};
#pragma unroll
        for (int m = 0; m < 2; ++m)
#pragma unroll
            for (int n = 0; n < 2; ++n)
#pragma unroll
                for (int r = 0; r < 4; ++r) {
                    float d = fmaf(-0.015625f, acc[m][n][r], w2v[n]);
                    unsigned ub = (__float_as_uint(d) & 0xFFFFF800u)
                                  | (unsigned)(cg0 + n * 16);
                    float df = __uint_as_float(ub);
                    int s = m * 4 + r;
                    b2[s] = __builtin_amdgcn_fmed3f(df, b1[s], b2[s]);
                    b1[s] = fminf(b1[s], df);
                }

        __syncthreads();
        cur ^= 1;
    }

    // cross-lane merge within 16-lane col groups, once per block
#pragma unroll
    for (int s = 0; s < 8; ++s) {
        float v1 = b1[s], v2 = b2[s];
#pragma unroll
        for (int msk = 1; msk < 16; msk <<= 1) {
            float o1 = __shfl_xor(v1, msk, 64);
            float o2 = __shfl_xor(v2, msk, 64);
            float hi = fmaxf(v1, o1);
            v1 = fminf(v1, o1);
            v2 = fminf(fminf(v2, o2), hi);
        }
        if (l15 == 0) {
            int row = rb * 64 + wr * 32 + (s >> 2) * 16 + g * 4 + (s & 3);
            top2[(size_t)row * 4 + wc * 2 + 0] = v1;
            top2[(size_t)row * 4 + wc * 2 + 1] = v2;
        }
    }
}

// ---- resolve: best of 4 candidates; exact fp32 re-score if within delta ----
__global__ __launch_bounds__(256) void vq_resolve(const float* __restrict__ top2,
                                                  const float* __restrict__ Z,
                                                  const float* __restrict__ Wd,
                                                  const float* __restrict__ w2,
                                                  int* __restrict__ assign)
{
    int row = blockIdx.x * 256 + threadIdx.x;
    float4 t4 = *reinterpret_cast<const float4*>(top2 + (size_t)row * 4);
    float vv[4] = {t4.x, t4.y, t4.z, t4.w};
    float dv[4];
    int dc[4];
#pragma unroll
    for (int i = 0; i < 4; ++i) {
        unsigned b = __float_as_uint(vv[i]);
        dc[i] = (int)(b & 2047u);
        dv[i] = __uint_as_float(b & 0xFFFFF800u);
    }
    int ib = 0;
#pragma unroll
    for (int i = 1; i < 4; ++i)
        if (dv[i] < dv[ib]) ib = i;
    float lim = dv[ib] + 6e-4f;
    int cols[4];
    int nc = 0;
#pragma unroll
    for (int i = 0; i < 4; ++i)
        if (dv[i] <= lim) cols[nc++] = dc[i];

    int res = dc[ib];
    if (nc > 1) {
        const float4* zp = reinterpret_cast<const float4*>(Z + (size_t)row * DD);
        float s0 = 0.f, s1 = 0.f, s2 = 0.f, s3 = 0.f;
        for (int q = 0; q < 32; ++q) {
            float4 z = zp[q];
            s0 = fmaf(z.x, z.x, s0);
            s1 = fmaf(z.y, z.y, s1);
            s2 = fmaf(z.z, z.z, s2);
            s3 = fmaf(z.w, z.w, s3);
        }
        float z2v = (s0 + s1) + (s2 + s3);
        unsigned long long be = ~0ull;
        for (int i = 0; i < nc; ++i) {
            int k = cols[i];
            const float4* wp = reinterpret_cast<const float4*>(Wd + (size_t)k * DD);
            float a0 = 0.f, a1 = 0.f, a2 = 0.f, a3 = 0.f;
            for (int q = 0; q < 32; ++q) {
                float4 zq = zp[q];
                float4 wq = wp[q];
                a0 = fmaf(zq.x, wq.x, a0);
                a1 = fmaf(zq.y, wq.y, a1);
                a2 = fmaf(zq.z, wq.z, a2);
                a3 = fmaf(zq.w, wq.w, a3);
            }
            float sdot = (a0 + a1) + (a2 + a3);
            float t = __fsub_rn(z2v, __fmul_rn(2.0f, sdot));
            float dist = __fadd_rn(t, w2[k]);
            unsigned long long key = (((unsigned long long)encf(dist)) << 32) | (unsigned)k;
            if (key < be) be = key;
        }
        res = (int)(be & 0xffffffffu);
    }
    assign[row] = res;
}

// ---- scatter: 1 element-atomic per thread, coalesced ----
__global__ __launch_bounds__(256) void vq_scatter(const float* __restrict__ Z,
                                                  const int* __restrict__ assign,
                                                  float* __restrict__ counts,
                                                  float* __restrict__ sums)
{
    int t = blockIdx.x * 256 + threadIdx.x;   // 0 .. N*D-1
    int row = t >> 7, d = t & 127;
    int k = assign[row];
    atomicAdd(&sums[(size_t)k * DD + d], Z[t]);
    if (d == 0) atomicAdd(&counts[k], 1.0f);
}

// ---- update: c_new, w_new ----
__global__ __launch_bounds__(256) void vq_update(const float* __restrict__ Wd,
                                                 const float* __restrict__ dict_cnt,
                                                 const float* __restrict__ counts,
                                                 const float* __restrict__ sums,
                                                 float* __restrict__ w_new_out,
                                                 float* __restrict__ c_new_out)
{
    int t = blockIdx.x * 256 + threadIdx.x;
    int k = t >> 7, d = t & 127;
    float cnt = dict_cnt[k];
    float ck = counts[k];
    bool assigned = ck > 0.f;
    float cn = assigned ? __fadd_rn(__fmul_rn(0.99f, cnt), __fmul_rn(0.01f, ck)) : cnt;
    float w = Wd[t];
    float wn = w;
    if (assigned) {
        float num = __fmul_rn(0.01f, sums[t]);
        wn = __fadd_rn(__fmul_rn(0.99f, w), num / fmaxf(cn, 1e-12f));
    }
    w_new_out[t] = wn;
    if (d == 0) c_new_out[k] = cn;
}

// ---- gather: st_out = w_new[i]; commit-loss partials ----
__global__ __launch_bounds__(256) void vq_gather(const float* __restrict__ Z,
                                                 const int* __restrict__ assign,
                                                 const float* __restrict__ w_new,
                                                 float* __restrict__ st_out,
                                                 float* __restrict__ loss_bins)
{
    int wave = threadIdx.x >> 6;
    int lane = threadIdx.x & 63;
    int row = blockIdx.x * 4 + wave;
    int k = assign[row];

    const float2* zp = reinterpret_cast<const float2*>(Z + (size_t)row * DD);
    const float2* wp = reinterpret_cast<const float2*>(w_new + (size_t)k * DD);
    float2 z = zp[lane];
    float2 w = wp[lane];
    reinterpret_cast<float2*>(st_out + (size_t)row * DD)[lane] = w;

    float dx = z.x - w.x, dy = z.y - w.y;
    float part = fmaf(dx, dx, dy * dy);
#pragma unroll
    for (int off = 32; off; off >>= 1) part += __shfl_down(part, off, 64);

    __shared__ float sm[4];
    if (lane == 0) sm[wave] = part;
    __syncthreads();
    if (threadIdx.x == 0) {
        float s = (sm[0] + sm[1]) + (sm[2] + sm[3]);
        atomicAdd(&loss_bins[(blockIdx.x & 255) * 16], s);
    }
}

__global__ void vq_finish(const float* __restrict__ loss_bins,
                          float* __restrict__ out_loss)
{
    if (threadIdx.x == 0) {
        float s = 0.f;
        for (int i = 0; i < 256; ++i) s += loss_bins[i * 16];
        out_loss[0] = s * (1.0f / 65536.0f);
    }
}

extern "C" void kernel_launch(void* const* d_in, const int* in_sizes, int n_in,
                              void* d_out, int out_size, void* d_ws, size_t ws_size,
                              hipStream_t stream)
{
    const float* Z        = (const float*)d_in[0];
    const float* Wd       = (const float*)d_in[1];
    const float* dict_cnt = (const float*)d_in[2];

    float* out      = (float*)d_out;
    float* st_out   = out;
    float* out_loss = out + (size_t)NN * DD;
    float* w_new    = out_loss + 1;
    float* c_new    = w_new + (size_t)KK * DD;

    char* ws = (char*)d_ws;
    _Float16* Zre = (_Float16*)ws;                       // 16,777,216 B
    _Float16* Wre = (_Float16*)(ws + 16777216);          //    524,288 B
    float* w2     = (float*)(ws + 17301504);             //      8,192 B
    float* top2   = (float*)(ws + 17309696);             //  1,048,576 B
    int* assign   = (int*)(ws + 18358272);               //    262,144 B
    float* counts = (float*)(ws + 18620416);             //      8,192 B
    float* sums   = (float*)(ws + 18628608);             //  1,048,576 B
    float* bins   = (float*)(ws + 19677184);             //     16,384 B

    // counts + sums + bins are contiguous: one memset
    hipMemsetAsync(counts, 0, 8192 + 1048576 + 16384, stream);

    vq_prep<<<(NN + KK) / 16, 256, 0, stream>>>(Z, Wd, Zre, Wre, w2);
    vq_gemm<<<NN / 64, 256, 0, stream>>>(Zre, Wre, w2, top2);
    vq_resolve<<<NN / 256, 256, 0, stream>>>(top2, Z, Wd, w2, assign);
    vq_scatter<<<(NN * DD) / 256, 256, 0, stream>>>(Z, assign, counts, sums);
    vq_update<<<(KK * DD) / 256, 256, 0, stream>>>(Wd, dict_cnt, counts, sums, w_new, c_new);
    vq_gather<<<NN / 4, 256, 0, stream>>>(Z, assign, w_new, st_out, bins);
    vq_finish<<<1, 64, 0, stream>>>(bins, out_loss);
}